// Round 3
// baseline (151.187 us; speedup 1.0000x reference)
//
#include <hip/hip_runtime.h>
#include <math.h>

#define RG_F     (8.3144621f / 96487.0f)          // R_GAS / F
#define INV_F    (1.0f / 96487.0f)
#define INV_SN   (1.0f / 0.000437545f)
#define INV_SP   (1.0f / 0.00030962f)
#define KN_C     2120.96f
#define KP_C     248898.0f
#define RO_C     0.117215f
#define INV_TDIFF (1.0f / 7000000.0f)
#define INV_TO   (1.0f / 6.08671f)
#define INV_TSN  (1.0f / 1001.38f)
#define INV_TSP  (1.0f / 46.4311f)
#define U0P_C    4.03f
#define U0N_C    0.01f
#define INV_VOLB (1.0f / 1.8e-05f)
#define INV_VOLS (1.0f / 2.0e-06f)
#define INV_QSMAX (1.0f / 1266.6666666666667f)    // 1 / (Q_MAX * VOL_S / VOL)
#define LN2_F    0.6931471805599453f

// hardware-rate ops (v_rcp_f32 / v_log_f32 / v_sqrt_f32, ~1 ulp)
__device__ __forceinline__ float hrcp(float x)  { return __builtin_amdgcn_rcpf(x); }
__device__ __forceinline__ float hlog(float x)  { return __builtin_amdgcn_logf(x) * LN2_F; } // ln
__device__ __forceinline__ float hsqrt(float x) { return __builtin_amdgcn_sqrtf(x); }

// asinh(x) = sign(x) * ln(|x| + sqrt(x^2+1)); args here are O(0.02..3), no overflow
__device__ __forceinline__ float fast_asinh(float x) {
    float ax = fabsf(x);
    float r  = hlog(ax + hsqrt(fmaf(ax, ax, 1.0f)));
    return copysignf(r, x);
}

__device__ __forceinline__ float ve_sum_p(float x) {
    const float A0  = -31593.7f;
    const float A1  = 0.106747f,   A2  = 24606.4f,   A3 = -78561.9f;
    const float A4  = 13317.9f,    A5  = 307387.0f,  A6 = 84916.1f;
    const float A7  = -1074690.0f, A8  = 2285.04f,   A9 = 990894.0f;
    const float A10 = 283920.0f,   A11 = -161513.0f, A12 = -469218.0f;

    float m  = 2.0f * x - 1.0f;
    float m2 = m * m;
    float tx = 2.0f * x * (1.0f - x);
    float s  = A0 * m;
    float pw = 1.0f;
    s = fmaf(A1  * pw, m2 - tx * 1.0f,  s); pw *= m;
    s = fmaf(A2  * pw, m2 - tx * 2.0f,  s); pw *= m;
    s = fmaf(A3  * pw, m2 - tx * 3.0f,  s); pw *= m;
    s = fmaf(A4  * pw, m2 - tx * 4.0f,  s); pw *= m;
    s = fmaf(A5  * pw, m2 - tx * 5.0f,  s); pw *= m;
    s = fmaf(A6  * pw, m2 - tx * 6.0f,  s); pw *= m;
    s = fmaf(A7  * pw, m2 - tx * 7.0f,  s); pw *= m;
    s = fmaf(A8  * pw, m2 - tx * 8.0f,  s); pw *= m;
    s = fmaf(A9  * pw, m2 - tx * 9.0f,  s); pw *= m;
    s = fmaf(A10 * pw, m2 - tx * 10.0f, s); pw *= m;
    s = fmaf(A11 * pw, m2 - tx * 11.0f, s); pw *= m;
    s = fmaf(A12 * pw, m2 - tx * 12.0f, s);
    return s * INV_F;
}

// one battery cell step: (i, s0, s1) -> (z, x0, x1)
__device__ __forceinline__ void cell_step(float i, float4 s0, float4 s1,
                                          float2& z, float4& x0, float4& x1) {
    const float Tb  = s0.x, Vo  = s0.y, Vsn = s0.z, Vsp = s0.w;
    const float qnB = s1.x, qnS = s1.y, qpB = s1.z, qpS = s1.w;

    const float xnS = qnS * INV_QSMAX;
    const float xpS = qpS * INV_QSMAX;

    const float qdDn = (qnB * INV_VOLB - qnS * INV_VOLS) * INV_TDIFF;
    const float qdDp = (qpB * INV_VOLB - qpS * INV_VOLS) * INV_TDIFF;

    // (1-x)^0.5 * x^0.5 = sqrt(x*(1-x))
    const float Jn0 = KN_C * hsqrt(xnS * (1.0f - xnS));
    const float Jp0 = KP_C * hsqrt(xpS * (1.0f - xpS));

    const float Jn = i * INV_SN;
    const float Jp = i * INV_SP;

    const float rtfa = 2.0f * RG_F * Tb;   // R*Tb/F/alpha, alpha=0.5
    const float VsnNom = rtfa * fast_asinh(Jn * 0.5f * hrcp(Jn0));
    const float VspNom = rtfa * fast_asinh(Jp * 0.5f * hrcp(Jp0));

    const float Vo_n  = Vo  + (i * RO_C  - Vo ) * INV_TO;
    const float Vsn_n = Vsn + (VsnNom    - Vsn) * INV_TSN;
    const float Vsp_n = Vsp + (VspNom    - Vsp) * INV_TSP;
    const float qnB_n = qnB - qdDn;
    const float qnS_n = qnS + (qdDn - i);
    const float qpB_n = qpB - qdDp;
    const float qpS_n = qpS + (i + qdDp);

    const float xn2 = qnS_n * INV_QSMAX;
    const float xp2 = qpS_n * INV_QSMAX;

    const float rtf = RG_F * Tb;
    // log((1-x)/x) via hw rcp + hw log
    const float Ven = U0N_C + rtf * hlog((1.0f - xn2) * hrcp(xn2))
                    + 86.19f * (2.0f * xn2 - 1.0f) * INV_F;   // AN poly: only A0 nonzero
    const float Vep = U0P_C + rtf * hlog((1.0f - xp2) * hrcp(xp2))
                    + ve_sum_p(xp2);

    const float V = Vep - Ven - Vo_n - Vsn_n - Vsp_n;

    z  = make_float2(Tb - 273.15f, V);
    x0 = make_float4(Tb, Vo_n, Vsn_n, Vsp_n);
    x1 = make_float4(qnB_n, qnS_n, qpB_n, qpS_n);
}

// 2 rows per thread: float4 Z-stores, ILP across two independent chains
__global__ __launch_bounds__(256) void battery_rnn_kernel(
    const float* __restrict__ cur,     // (B,1)
    const float* __restrict__ states,  // (B,8)
    float* __restrict__ outZ,          // (B,2)
    float* __restrict__ outX,          // (B,8)
    int n)
{
    const int t   = blockIdx.x * blockDim.x + threadIdx.x;
    const int idx = t * 2;
    if (idx + 1 >= n) {
        if (idx < n) {  // odd-n tail (not hit for B=2^21, kept for safety)
            float4 s0 = *reinterpret_cast<const float4*>(states + (size_t)idx * 8);
            float4 s1 = *reinterpret_cast<const float4*>(states + (size_t)idx * 8 + 4);
            float2 z; float4 x0, x1;
            cell_step(cur[idx], s0, s1, z, x0, x1);
            *reinterpret_cast<float2*>(outZ + (size_t)idx * 2) = z;
            *reinterpret_cast<float4*>(outX + (size_t)idx * 8) = x0;
            *reinterpret_cast<float4*>(outX + (size_t)idx * 8 + 4) = x1;
        }
        return;
    }

    const float2 ii = *reinterpret_cast<const float2*>(cur + idx);
    const float4 a0 = *reinterpret_cast<const float4*>(states + (size_t)idx * 8);
    const float4 a1 = *reinterpret_cast<const float4*>(states + (size_t)idx * 8 + 4);
    const float4 b0 = *reinterpret_cast<const float4*>(states + (size_t)idx * 8 + 8);
    const float4 b1 = *reinterpret_cast<const float4*>(states + (size_t)idx * 8 + 12);

    float2 za, zb; float4 xa0, xa1, xb0, xb1;
    cell_step(ii.x, a0, a1, za, xa0, xa1);
    cell_step(ii.y, b0, b1, zb, xb0, xb1);

    *reinterpret_cast<float4*>(outZ + (size_t)idx * 2) =
        make_float4(za.x, za.y, zb.x, zb.y);
    float4* xo = reinterpret_cast<float4*>(outX + (size_t)idx * 8);
    xo[0] = xa0; xo[1] = xa1; xo[2] = xb0; xo[3] = xb1;
}

extern "C" void kernel_launch(void* const* d_in, const int* in_sizes, int n_in,
                              void* d_out, int out_size, void* d_ws, size_t ws_size,
                              hipStream_t stream) {
    const float* cur    = (const float*)d_in[0];   // inputs (B,1)
    const float* states = (const float*)d_in[1];   // states (B,8)
    const int n = in_sizes[0];                      // B

    float* outZ = (float*)d_out;                    // first B*2 floats
    float* outX = (float*)d_out + 2 * (size_t)n;    // next  B*8 floats

    const int block = 256;
    const int nthreads = (n + 1) / 2;
    const int grid  = (nthreads + block - 1) / block;
    battery_rnn_kernel<<<grid, block, 0, stream>>>(cur, states, outZ, outX, n);
}

// Round 4
// 141.859 us; speedup vs baseline: 1.0658x; 1.0658x over previous
//
#include <hip/hip_runtime.h>
#include <math.h>

#define RG_F     (8.3144621f / 96487.0f)          // R_GAS / F
#define INV_F    (1.0f / 96487.0f)
#define INV_SN   (1.0f / 0.000437545f)
#define INV_SP   (1.0f / 0.00030962f)
#define KN_C     2120.96f
#define KP_C     248898.0f
#define RO_C     0.117215f
#define INV_TDIFF (1.0f / 7000000.0f)
#define INV_TO   (1.0f / 6.08671f)
#define INV_TSN  (1.0f / 1001.38f)
#define INV_TSP  (1.0f / 46.4311f)
#define U0P_C    4.03f
#define U0N_C    0.01f
#define INV_VOLB (1.0f / 1.8e-05f)
#define INV_VOLS (1.0f / 2.0e-06f)
#define INV_QSMAX (1.0f / 1266.6666666666667f)    // 1 / (Q_MAX * VOL_S / VOL)
#define LN2_F    0.6931471805599453f

#define BLOCK 256
#define LDS_STRIDE 10   // floats per row in LDS; 10 dwords -> bank pair (5r)%16, 5 coprime 16 => conflict-free

// hardware-rate ops (v_rcp_f32 / v_log_f32 / v_sqrt_f32, ~1 ulp)
__device__ __forceinline__ float hrcp(float x)  { return __builtin_amdgcn_rcpf(x); }
__device__ __forceinline__ float hlog(float x)  { return __builtin_amdgcn_logf(x) * LN2_F; } // ln
__device__ __forceinline__ float hsqrt(float x) { return __builtin_amdgcn_sqrtf(x); }

// asinh(x) = sign(x) * ln(|x| + sqrt(x^2+1)); args here are O(0.02..3), no overflow
__device__ __forceinline__ float fast_asinh(float x) {
    float ax = fabsf(x);
    float r  = hlog(ax + hsqrt(fmaf(ax, ax, 1.0f)));
    return copysignf(r, x);
}

__device__ __forceinline__ float ve_sum_p(float x) {
    const float A0  = -31593.7f;
    const float A1  = 0.106747f,   A2  = 24606.4f,   A3 = -78561.9f;
    const float A4  = 13317.9f,    A5  = 307387.0f,  A6 = 84916.1f;
    const float A7  = -1074690.0f, A8  = 2285.04f,   A9 = 990894.0f;
    const float A10 = 283920.0f,   A11 = -161513.0f, A12 = -469218.0f;

    float m  = 2.0f * x - 1.0f;
    float m2 = m * m;
    float tx = 2.0f * x * (1.0f - x);
    float s  = A0 * m;
    float pw = 1.0f;
    s = fmaf(A1  * pw, m2 - tx * 1.0f,  s); pw *= m;
    s = fmaf(A2  * pw, m2 - tx * 2.0f,  s); pw *= m;
    s = fmaf(A3  * pw, m2 - tx * 3.0f,  s); pw *= m;
    s = fmaf(A4  * pw, m2 - tx * 4.0f,  s); pw *= m;
    s = fmaf(A5  * pw, m2 - tx * 5.0f,  s); pw *= m;
    s = fmaf(A6  * pw, m2 - tx * 6.0f,  s); pw *= m;
    s = fmaf(A7  * pw, m2 - tx * 7.0f,  s); pw *= m;
    s = fmaf(A8  * pw, m2 - tx * 8.0f,  s); pw *= m;
    s = fmaf(A9  * pw, m2 - tx * 9.0f,  s); pw *= m;
    s = fmaf(A10 * pw, m2 - tx * 10.0f, s); pw *= m;
    s = fmaf(A11 * pw, m2 - tx * 11.0f, s); pw *= m;
    s = fmaf(A12 * pw, m2 - tx * 12.0f, s);
    return s * INV_F;
}

__global__ __launch_bounds__(256) void battery_rnn_kernel(
    const float* __restrict__ cur,     // (B,1)
    const float* __restrict__ states,  // (B,8)
    float* __restrict__ outZ,          // (B,2)
    float* __restrict__ outX,          // (B,8)
    int n)
{
    __shared__ float lds[BLOCK * LDS_STRIDE];   // 10.0 KiB

    const int tid     = threadIdx.x;
    const int rowBase = blockIdx.x * BLOCK;
    const int row     = rowBase + tid;

    // ---- stage in: coalesced global float4 (lane l <-> bytes l*16) -> padded LDS ----
    const float* gsrc = states + (size_t)rowBase * 8;
    #pragma unroll
    for (int k = 0; k < 2; ++k) {
        const int c = tid + k * BLOCK;      // chunk index: row r = c>>1, half h = c&1
        const int r = c >> 1, h = c & 1;
        if (rowBase + r < n) {
            const float4 v = *reinterpret_cast<const float4*>(gsrc + (size_t)c * 4);
            float* dst = &lds[r * LDS_STRIDE + h * 4];       // byte addr r*40+h*16, 8B-aligned
            reinterpret_cast<float2*>(dst)[0] = make_float2(v.x, v.y);
            reinterpret_cast<float2*>(dst)[1] = make_float2(v.z, v.w);
        }
    }
    __syncthreads();

    // ---- read own row from LDS, compute, write results back in place ----
    if (row < n) {
        const float* src = &lds[tid * LDS_STRIDE];
        const float2 p0 = reinterpret_cast<const float2*>(src)[0];
        const float2 p1 = reinterpret_cast<const float2*>(src)[1];
        const float2 p2 = reinterpret_cast<const float2*>(src)[2];
        const float2 p3 = reinterpret_cast<const float2*>(src)[3];
        const float i   = cur[row];

        const float Tb  = p0.x, Vo  = p0.y, Vsn = p1.x, Vsp = p1.y;
        const float qnB = p2.x, qnS = p2.y, qpB = p3.x, qpS = p3.y;

        const float xnS = qnS * INV_QSMAX;
        const float xpS = qpS * INV_QSMAX;

        const float qdDn = (qnB * INV_VOLB - qnS * INV_VOLS) * INV_TDIFF;
        const float qdDp = (qpB * INV_VOLB - qpS * INV_VOLS) * INV_TDIFF;

        // (1-x)^0.5 * x^0.5 = sqrt(x*(1-x))
        const float Jn0 = KN_C * hsqrt(xnS * (1.0f - xnS));
        const float Jp0 = KP_C * hsqrt(xpS * (1.0f - xpS));

        const float Jn = i * INV_SN;
        const float Jp = i * INV_SP;

        const float rtfa = 2.0f * RG_F * Tb;   // R*Tb/F/alpha, alpha=0.5
        const float VsnNom = rtfa * fast_asinh(Jn * 0.5f * hrcp(Jn0));
        const float VspNom = rtfa * fast_asinh(Jp * 0.5f * hrcp(Jp0));

        const float Vo_n  = Vo  + (i * RO_C  - Vo ) * INV_TO;
        const float Vsn_n = Vsn + (VsnNom    - Vsn) * INV_TSN;
        const float Vsp_n = Vsp + (VspNom    - Vsp) * INV_TSP;
        const float qnB_n = qnB - qdDn;
        const float qnS_n = qnS + (qdDn - i);
        const float qpB_n = qpB - qdDp;
        const float qpS_n = qpS + (i + qdDp);

        const float xn2 = qnS_n * INV_QSMAX;
        const float xp2 = qpS_n * INV_QSMAX;

        const float rtf = RG_F * Tb;
        const float Ven = U0N_C + rtf * hlog((1.0f - xn2) * hrcp(xn2))
                        + 86.19f * (2.0f * xn2 - 1.0f) * INV_F;   // AN poly: only A0 nonzero
        const float Vep = U0P_C + rtf * hlog((1.0f - xp2) * hrcp(xp2))
                        + ve_sum_p(xp2);

        const float V = Vep - Ven - Vo_n - Vsn_n - Vsp_n;

        // Z store is already coalesced (8 B/lane contiguous) -> direct global
        *reinterpret_cast<float2*>(outZ + (size_t)row * 2) =
            make_float2(Tb - 273.15f, V);

        // write X_next row back into own LDS row (only this thread touches it)
        float* dst = &lds[tid * LDS_STRIDE];
        reinterpret_cast<float2*>(dst)[0] = make_float2(Tb,    Vo_n);
        reinterpret_cast<float2*>(dst)[1] = make_float2(Vsn_n, Vsp_n);
        reinterpret_cast<float2*>(dst)[2] = make_float2(qnB_n, qnS_n);
        reinterpret_cast<float2*>(dst)[3] = make_float2(qpB_n, qpS_n);
    }
    __syncthreads();

    // ---- de-stage: padded LDS -> coalesced global float4 ----
    float* gdst = outX + (size_t)rowBase * 8;
    #pragma unroll
    for (int k = 0; k < 2; ++k) {
        const int c = tid + k * BLOCK;
        const int r = c >> 1, h = c & 1;
        if (rowBase + r < n) {
            const float* src = &lds[r * LDS_STRIDE + h * 4];
            const float2 a = reinterpret_cast<const float2*>(src)[0];
            const float2 b = reinterpret_cast<const float2*>(src)[1];
            *reinterpret_cast<float4*>(gdst + (size_t)c * 4) =
                make_float4(a.x, a.y, b.x, b.y);
        }
    }
}

extern "C" void kernel_launch(void* const* d_in, const int* in_sizes, int n_in,
                              void* d_out, int out_size, void* d_ws, size_t ws_size,
                              hipStream_t stream) {
    const float* cur    = (const float*)d_in[0];   // inputs (B,1)
    const float* states = (const float*)d_in[1];   // states (B,8)
    const int n = in_sizes[0];                      // B

    float* outZ = (float*)d_out;                    // first B*2 floats
    float* outX = (float*)d_out + 2 * (size_t)n;    // next  B*8 floats

    const int grid = (n + BLOCK - 1) / BLOCK;
    battery_rnn_kernel<<<grid, BLOCK, 0, stream>>>(cur, states, outZ, outX, n);
}